// Round 1
// baseline (37.965 us; speedup 1.0000x reference)
//
#include <hip/hip_runtime.h>

// HSTU block preprocessor: jagged concat of [ctx1 | ctx2 | interleave(item, action)]
// per sample, plus merged lengths. Pure memory-bound row gather/copy.
//
// D = 512 floats per row (128 float4). One wave (64 lanes) copies one row:
// lane moves float4 at col=lane and col=lane+64 (fully coalesced, 1 KiB/instr).

#define HSTU_D 512
#define F4_PER_ROW (HSTU_D / 4)   // 128
#define MAX_B 1024                // LDS sized for up to 1024 samples (B=128 here)

__global__ void hstu_lengths_kernel(const int* __restrict__ it_off,
                                    const int* __restrict__ c1_off,
                                    const int* __restrict__ c2_off,
                                    float* __restrict__ out_len, int B) {
    int b = blockIdx.x * blockDim.x + threadIdx.x;
    if (b < B) {
        int len = (c1_off[b + 1] - c1_off[b]) + (c2_off[b + 1] - c2_off[b])
                + 2 * (it_off[b + 1] - it_off[b]);
        out_len[b] = (float)len;
    }
}

__global__ __launch_bounds__(256) void hstu_concat_kernel(
    const float4* __restrict__ item, const float4* __restrict__ action,
    const float4* __restrict__ ctx1, const float4* __restrict__ ctx2,
    const int* __restrict__ it_off, const int* __restrict__ c1_off,
    const int* __restrict__ c2_off,
    float4* __restrict__ out, int B, int total_rows) {
    __shared__ int s_it[MAX_B + 1], s_c1[MAX_B + 1], s_c2[MAX_B + 1], s_base[MAX_B + 1];

    for (int i = threadIdx.x; i <= B; i += blockDim.x) {
        int a  = it_off[i];
        int b1 = c1_off[i];
        int b2 = c2_off[i];
        s_it[i]   = a;
        s_c1[i]   = b1;
        s_c2[i]   = b2;
        s_base[i] = b1 + b2 + 2 * a;   // output row offset of sample i
    }
    __syncthreads();

    const int wave = threadIdx.x >> 6;      // 0..3
    const int lane = threadIdx.x & 63;
    const int row  = blockIdx.x * 4 + wave; // output row this wave copies
    if (row >= total_rows) return;

    // Largest b with s_base[b] <= row. Invariant: s_base[lo] <= row < s_base[hi].
    int lo = 0, hi = B;
    while (hi - lo > 1) {
        int mid = (lo + hi) >> 1;
        if (s_base[mid] <= row) lo = mid; else hi = mid;
    }
    const int b     = lo;
    const int local = row - s_base[b];
    const int l1    = s_c1[b + 1] - s_c1[b];
    const int l2    = s_c2[b + 1] - s_c2[b];

    const float4* __restrict__ src;
    if (local < l1) {
        src = ctx1 + (size_t)(s_c1[b] + local) * F4_PER_ROW;
    } else if (local < l1 + l2) {
        src = ctx2 + (size_t)(s_c2[b] + (local - l1)) * F4_PER_ROW;
    } else {
        int t = local - l1 - l2;               // position within interleaved block
        int r = s_it[b] + (t >> 1);            // source item/action row
        src = ((t & 1) ? action : item) + (size_t)r * F4_PER_ROW;
    }

    float4* __restrict__ dst = out + (size_t)row * F4_PER_ROW;
    dst[lane]      = src[lane];
    dst[lane + 64] = src[lane + 64];
}

extern "C" void kernel_launch(void* const* d_in, const int* in_sizes, int n_in,
                              void* d_out, int out_size, void* d_ws, size_t ws_size,
                              hipStream_t stream) {
    const float4* item   = (const float4*)d_in[0];
    const float4* action = (const float4*)d_in[1];
    const float4* ctx1   = (const float4*)d_in[2];
    const float4* ctx2   = (const float4*)d_in[3];
    const int* it_off    = (const int*)d_in[4];
    const int* c1_off    = (const int*)d_in[5];
    const int* c2_off    = (const int*)d_in[6];

    const int B = in_sizes[4] - 1;
    const long long total_elems = (long long)in_sizes[0] + in_sizes[1]
                                + in_sizes[2] + in_sizes[3];
    const int total_rows = (int)(total_elems / HSTU_D);

    float* out     = (float*)d_out;
    float* out_len = out + (size_t)total_rows * HSTU_D;  // lengths tail

    const int grid = (total_rows + 3) / 4;  // 4 rows (waves) per 256-thread block
    hstu_concat_kernel<<<grid, 256, 0, stream>>>(
        item, action, ctx1, ctx2, it_off, c1_off, c2_off,
        (float4*)out, B, total_rows);

    hstu_lengths_kernel<<<(B + 127) / 128, 128, 0, stream>>>(
        it_off, c1_off, c2_off, out_len, B);
}

// Round 2
// 35.278 us; speedup vs baseline: 1.0762x; 1.0762x over previous
//
#include <hip/hip_runtime.h>

// HSTU block preprocessor: jagged concat of [ctx1 | ctx2 | interleave(item, action)]
// per sample, plus merged lengths (fused: block 0 writes lengths).
// Pure memory-bound row gather/copy. One wave (64 lanes) copies one 2 KiB row.

#define HSTU_D 512
#define F4_PER_ROW (HSTU_D / 4)   // 128
#define MAX_B 1024                // LDS sized for up to 1024 samples (B=128 here)

typedef float f32x4 __attribute__((ext_vector_type(4)));

__global__ __launch_bounds__(256) void hstu_concat_kernel(
    const f32x4* __restrict__ item, const f32x4* __restrict__ action,
    const f32x4* __restrict__ ctx1, const f32x4* __restrict__ ctx2,
    const int* __restrict__ it_off, const int* __restrict__ c1_off,
    const int* __restrict__ c2_off,
    f32x4* __restrict__ out, float* __restrict__ out_len,
    int B, int total_rows) {
    __shared__ int s_it[MAX_B + 1], s_c1[MAX_B + 1], s_c2[MAX_B + 1], s_base[MAX_B + 1];

    for (int i = threadIdx.x; i <= B; i += blockDim.x) {
        int a  = it_off[i];
        int b1 = c1_off[i];
        int b2 = c2_off[i];
        s_it[i]   = a;
        s_c1[i]   = b1;
        s_c2[i]   = b2;
        s_base[i] = b1 + b2 + 2 * a;   // output row offset of sample i
    }
    __syncthreads();

    // Fused lengths write: block 0 only (128 values).
    if (blockIdx.x == 0 && (int)threadIdx.x < B) {
        int i = threadIdx.x;
        int len = (s_c1[i + 1] - s_c1[i]) + (s_c2[i + 1] - s_c2[i])
                + 2 * (s_it[i + 1] - s_it[i]);
        out_len[i] = (float)len;
    }

    const int wave = threadIdx.x >> 6;      // 0..3
    const int lane = threadIdx.x & 63;
    const int row  = blockIdx.x * 4 + wave; // output row this wave copies
    if (row >= total_rows) return;

    // Largest b with s_base[b] <= row. Invariant: s_base[lo] <= row < s_base[hi].
    int lo = 0, hi = B;
    while (hi - lo > 1) {
        int mid = (lo + hi) >> 1;
        if (s_base[mid] <= row) lo = mid; else hi = mid;
    }
    const int b     = lo;
    const int local = row - s_base[b];
    const int l1    = s_c1[b + 1] - s_c1[b];
    const int l2    = s_c2[b + 1] - s_c2[b];

    const f32x4* __restrict__ src;
    if (local < l1) {
        src = ctx1 + (size_t)(s_c1[b] + local) * F4_PER_ROW;
    } else if (local < l1 + l2) {
        src = ctx2 + (size_t)(s_c2[b] + (local - l1)) * F4_PER_ROW;
    } else {
        int t = local - l1 - l2;               // position within interleaved block
        int r = s_it[b] + (t >> 1);            // source item/action row
        src = ((t & 1) ? action : item) + (size_t)r * F4_PER_ROW;
    }

    f32x4* __restrict__ dst = out + (size_t)row * F4_PER_ROW;
    f32x4 v0 = src[lane];
    f32x4 v1 = src[lane + 64];
    __builtin_nontemporal_store(v0, dst + lane);
    __builtin_nontemporal_store(v1, dst + lane + 64);
}

extern "C" void kernel_launch(void* const* d_in, const int* in_sizes, int n_in,
                              void* d_out, int out_size, void* d_ws, size_t ws_size,
                              hipStream_t stream) {
    const f32x4* item   = (const f32x4*)d_in[0];
    const f32x4* action = (const f32x4*)d_in[1];
    const f32x4* ctx1   = (const f32x4*)d_in[2];
    const f32x4* ctx2   = (const f32x4*)d_in[3];
    const int* it_off   = (const int*)d_in[4];
    const int* c1_off   = (const int*)d_in[5];
    const int* c2_off   = (const int*)d_in[6];

    const int B = in_sizes[4] - 1;
    const long long total_elems = (long long)in_sizes[0] + in_sizes[1]
                                + in_sizes[2] + in_sizes[3];
    const int total_rows = (int)(total_elems / HSTU_D);

    float* out     = (float*)d_out;
    float* out_len = out + (size_t)total_rows * HSTU_D;  // lengths tail

    const int grid = (total_rows + 3) / 4;  // 4 rows (waves) per 256-thread block
    hstu_concat_kernel<<<grid, 256, 0, stream>>>(
        item, action, ctx1, ctx2, it_off, c1_off, c2_off,
        (f32x4*)out, out_len, B, total_rows);
}